// Round 1
// baseline (157.894 us; speedup 1.0000x reference)
//
#include <hip/hip_runtime.h>

// Problem constants
#define NN 8192
#define EE 65536
#define IN_C 64
#define L1C 48
#define L2C 32
#define OUT_C 16
#define EF 8

// T1 columns: 8 weight slices (8*48) + bias-matrix (48) + root1 (48) = 480
#define T1_COLS 480
// T2 columns: 8 weight slices (8*32) + bias-matrix (32) + root2 (32) = 320
#define T2_COLS 320

// ---------------------------------------------------------------------------
// k_T1: T1[n][c] = sum_i x[n][i] * Wcol[c][i], Wcol stride 48.
//   c in [0,384): f=c/48, W = nn1_w[f*3072 + i*48 + o]
//   c in [384,432): nn1_b[i*48+o]   (bias reshaped (64,48))
//   c in [432,480): root1[i*48+o]
// 16 nodes per block; x tile transposed in LDS so the n-dimension vectorizes.
// ---------------------------------------------------------------------------
__global__ __launch_bounds__(256) void k_T1(const float* __restrict__ x,
                                            const float* __restrict__ w,
                                            const float* __restrict__ b,
                                            const float* __restrict__ root,
                                            float* __restrict__ T1) {
    __shared__ float xsT[64 * 16];  // [i][n]
    const int n0 = blockIdx.x * 16;
    for (int t = threadIdx.x; t < 16 * 64; t += 256) {
        int n = t >> 6, i = t & 63;
        xsT[i * 16 + n] = x[(n0 + n) * 64 + i];
    }
    __syncthreads();
    for (int c = threadIdx.x; c < T1_COLS; c += 256) {
        int f = c / 48, o = c - f * 48;
        const float* wp;
        if (f < 8)      wp = w + f * 3072 + o;
        else if (f == 8) wp = b + o;
        else             wp = root + o;
        float acc[16];
#pragma unroll
        for (int n = 0; n < 16; n++) acc[n] = 0.f;
#pragma unroll 16
        for (int i = 0; i < 64; i++) {
            float wv = wp[i * 48];
            const float* xr = &xsT[i * 16];
#pragma unroll
            for (int n = 0; n < 16; n++) acc[n] += xr[n] * wv;
        }
#pragma unroll
        for (int n = 0; n < 16; n++) T1[(size_t)(n0 + n) * T1_COLS + c] = acc[n];
    }
}

// k_T2: same but K=48, col stride 32, inputs h1.
__global__ __launch_bounds__(256) void k_T2(const float* __restrict__ h1,
                                            const float* __restrict__ w,
                                            const float* __restrict__ b,
                                            const float* __restrict__ root,
                                            float* __restrict__ T2) {
    __shared__ float xsT[48 * 16];
    const int n0 = blockIdx.x * 16;
    for (int t = threadIdx.x; t < 16 * 48; t += 256) {
        int n = t / 48, i = t - n * 48;
        xsT[i * 16 + n] = h1[(n0 + n) * 48 + i];
    }
    __syncthreads();
    for (int c = threadIdx.x; c < T2_COLS; c += 256) {
        int f = c >> 5, o = c & 31;
        const float* wp;
        if (f < 8)      wp = w + f * 1536 + o;
        else if (f == 8) wp = b + o;
        else             wp = root + o;
        float acc[16];
#pragma unroll
        for (int n = 0; n < 16; n++) acc[n] = 0.f;
#pragma unroll 16
        for (int i = 0; i < 48; i++) {
            float wv = wp[i * 32];
            const float* xr = &xsT[i * 16];
#pragma unroll
            for (int n = 0; n < 16; n++) acc[n] += xr[n] * wv;
        }
#pragma unroll
        for (int n = 0; n < 16; n++) T2[(size_t)(n0 + n) * T2_COLS + c] = acc[n];
    }
}

__global__ __launch_bounds__(256) void k_zero(float* __restrict__ p, int n4) {
    int i = blockIdx.x * 256 + threadIdx.x;
    if (i < n4) ((float4*)p)[i] = make_float4(0.f, 0.f, 0.f, 0.f);
}

// k_edge1: msg[e,o] = sum_f ea[e,f]*T1[src][f*48+o] + T1[src][384+o]; scatter to agg1[dst]
__global__ __launch_bounds__(256) void k_edge1(const int* __restrict__ ei,
                                               const float* __restrict__ ea,
                                               const float* __restrict__ T1,
                                               float* __restrict__ agg1) {
    int idx = blockIdx.x * 256 + threadIdx.x;
    int e = idx / 48, o = idx - e * 48;
    if (e >= EE) return;
    int s = ei[e], d = ei[EE + e];
    const float* t = T1 + (size_t)s * T1_COLS + o;
    const float4* a4 = (const float4*)(ea + (size_t)e * 8);
    float4 a0 = a4[0], a1 = a4[1];
    float m = t[384];
    m += a0.x * t[0 * 48];
    m += a0.y * t[1 * 48];
    m += a0.z * t[2 * 48];
    m += a0.w * t[3 * 48];
    m += a1.x * t[4 * 48];
    m += a1.y * t[5 * 48];
    m += a1.z * t[6 * 48];
    m += a1.w * t[7 * 48];
    atomicAdd(agg1 + (size_t)d * 48 + o, m);
}

__global__ __launch_bounds__(256) void k_h1(const float* __restrict__ agg1,
                                            const float* __restrict__ T1,
                                            const float* __restrict__ bias1,
                                            float* __restrict__ h1) {
    int idx = blockIdx.x * 256 + threadIdx.x;
    if (idx >= NN * 48) return;
    int n = idx / 48, o = idx - n * 48;
    float v = agg1[idx] + T1[(size_t)n * T1_COLS + 432 + o] + bias1[o];
    h1[idx] = v > 0.f ? v : 0.f;
}

// k_edge2: layer-2 scatter + degree count
__global__ __launch_bounds__(256) void k_edge2(const int* __restrict__ ei,
                                               const float* __restrict__ ea,
                                               const float* __restrict__ T2,
                                               float* __restrict__ agg2,
                                               float* __restrict__ deg) {
    int idx = blockIdx.x * 256 + threadIdx.x;
    int e = idx >> 5, o = idx & 31;
    if (e >= EE) return;
    int s = ei[e], d = ei[EE + e];
    const float* t = T2 + (size_t)s * T2_COLS + o;
    const float4* a4 = (const float4*)(ea + (size_t)e * 8);
    float4 a0 = a4[0], a1 = a4[1];
    float m = t[256];
    m += a0.x * t[0 * 32];
    m += a0.y * t[1 * 32];
    m += a0.z * t[2 * 32];
    m += a0.w * t[3 * 32];
    m += a1.x * t[4 * 32];
    m += a1.y * t[5 * 32];
    m += a1.z * t[6 * 32];
    m += a1.w * t[7 * 32];
    atomicAdd(agg2 + (size_t)d * 32 + o, m);
    if (o == 0) atomicAdd(deg + d, 1.0f);
}

// k_post: h2 = relu(agg2 + root-part + bias2); hmu = h2@mu_w; hls = h2@ls_w;
// init out with self-loop term + bias; store hmu/hls/dinv for edge scatter.
__global__ __launch_bounds__(256) void k_post(const float* __restrict__ agg2,
                                              const float* __restrict__ T2,
                                              const float* __restrict__ bias2,
                                              const float* __restrict__ mu_w,
                                              const float* __restrict__ mu_b,
                                              const float* __restrict__ ls_w,
                                              const float* __restrict__ ls_b,
                                              const float* __restrict__ deg,
                                              float* __restrict__ hmu,
                                              float* __restrict__ hls,
                                              float* __restrict__ dinv,
                                              float* __restrict__ out) {
    __shared__ float h2s[8][32];
    const int n0 = blockIdx.x * 8;
    const int lid = threadIdx.x >> 5;
    const int o = threadIdx.x & 31;
    const int n = n0 + lid;
    float v = agg2[(size_t)n * 32 + o] + T2[(size_t)n * T2_COLS + 288 + o] + bias2[o];
    v = v > 0.f ? v : 0.f;
    h2s[lid][o] = v;
    __syncthreads();
    const float* wm = (o < 16) ? mu_w : ls_w;
    const float* bb = (o < 16) ? mu_b : ls_b;
    const int oo = o & 15;
    float acc = 0.f;
#pragma unroll
    for (int i = 0; i < 32; i++) acc += h2s[lid][i] * wm[i * 16 + oo];
    float d = deg[n] + 1.0f;
    float di = rsqrtf(d);
    if (o == 0) dinv[n] = di;
    float init = acc / d + bb[oo];
    if (o < 16) {
        hmu[(size_t)n * 16 + oo] = acc;
        out[(size_t)n * 16 + oo] = init;
    } else {
        hls[(size_t)n * 16 + oo] = acc;
        out[(size_t)NN * 16 + (size_t)n * 16 + oo] = init;
    }
}

__global__ __launch_bounds__(256) void k_gcn_edge(const int* __restrict__ ei,
                                                  const float* __restrict__ hmu,
                                                  const float* __restrict__ hls,
                                                  const float* __restrict__ dinv,
                                                  float* __restrict__ out) {
    int idx = blockIdx.x * 256 + threadIdx.x;
    int e = idx >> 4, o = idx & 15;
    if (e >= EE) return;
    int s = ei[e], d = ei[EE + e];
    float norm = dinv[s] * dinv[d];
    atomicAdd(out + (size_t)d * 16 + o, hmu[(size_t)s * 16 + o] * norm);
    atomicAdd(out + (size_t)NN * 16 + (size_t)d * 16 + o, hls[(size_t)s * 16 + o] * norm);
}

extern "C" void kernel_launch(void* const* d_in, const int* in_sizes, int n_in,
                              void* d_out, int out_size, void* d_ws, size_t ws_size,
                              hipStream_t stream) {
    const float* x     = (const float*)d_in[0];
    const int*   ei    = (const int*)d_in[1];
    const float* ea    = (const float*)d_in[2];
    const float* nn1_w = (const float*)d_in[3];
    const float* nn1_b = (const float*)d_in[4];
    const float* root1 = (const float*)d_in[5];
    const float* bias1 = (const float*)d_in[6];
    const float* nn2_w = (const float*)d_in[7];
    const float* nn2_b = (const float*)d_in[8];
    const float* root2 = (const float*)d_in[9];
    const float* bias2 = (const float*)d_in[10];
    const float* mu_w  = (const float*)d_in[11];
    const float* mu_b  = (const float*)d_in[12];
    const float* ls_w  = (const float*)d_in[13];
    const float* ls_b  = (const float*)d_in[14];
    float* out = (float*)d_out;

    // Workspace layout (floats). T2 aliases T1 (T1 dead after k_h1).
    float* W    = (float*)d_ws;
    float* T1   = W;                       // 8192*480 = 3,932,160
    float* T2   = W;                       // alias
    float* agg1 = W + 3932160;             // 393,216
    float* agg2 = agg1 + 393216;           // 262,144
    float* deg  = agg2 + 262144;           // 8,192
    float* h1   = deg + 8192;              // 393,216
    float* hmu  = h1 + 393216;             // 131,072
    float* hls  = hmu + 131072;            // 131,072
    float* dinv = hls + 131072;            // 8,192
    // total ~21 MB

    // agg1+agg2+deg are contiguous: zero in one pass (663,552 floats = 165,888 float4)
    k_T1<<<dim3(NN / 16), dim3(256), 0, stream>>>(x, nn1_w, nn1_b, root1, T1);
    k_zero<<<dim3((165888 + 255) / 256), dim3(256), 0, stream>>>(agg1, 165888);
    k_edge1<<<dim3((EE * 48) / 256), dim3(256), 0, stream>>>(ei, ea, T1, agg1);
    k_h1<<<dim3((NN * 48) / 256), dim3(256), 0, stream>>>(agg1, T1, bias1, h1);
    k_T2<<<dim3(NN / 16), dim3(256), 0, stream>>>(h1, nn2_w, nn2_b, root2, T2);
    k_edge2<<<dim3((EE * 32) / 256), dim3(256), 0, stream>>>(ei, ea, T2, agg2, deg);
    k_post<<<dim3(NN / 8), dim3(256), 0, stream>>>(agg2, T2, bias2, mu_w, mu_b,
                                                   ls_w, ls_b, deg, hmu, hls, dinv, out);
    k_gcn_edge<<<dim3((EE * 16) / 256), dim3(256), 0, stream>>>(ei, hmu, hls, dinv, out);
}